// Round 1
// baseline (777.070 us; speedup 1.0000x reference)
//
#include <hip/hip_runtime.h>
#include <cstdint>

#define TPB 256

__device__ __forceinline__ float lrelu(float x) { return x > 0.0f ? x : 0.2f * x; }

// ---------------- graph build ----------------
__global__ void k_setflag(const int* __restrict__ midx, int* __restrict__ flag, int m) {
    int i = blockIdx.x * TPB + threadIdx.x;
    if (i < m) flag[midx[i]] = 1;
}

__global__ void k_count(const int* __restrict__ dst, int* __restrict__ cnt, int e) {
    int i = blockIdx.x * TPB + threadIdx.x;
    if (i < e) atomicAdd(&cnt[dst[i]], 1);
}

// exclusive scan, 2048 elements per block
__global__ void k_scan_block(const int* __restrict__ cnt, int* __restrict__ rp,
                             int* __restrict__ bsum, int n) {
    __shared__ int ls[TPB];
    int t = threadIdx.x, b = blockIdx.x;
    int base = b * 2048 + t * 8;
    int c[8];
    int tsum = 0;
#pragma unroll
    for (int j = 0; j < 8; ++j) {
        int idx = base + j;
        c[j] = (idx < n) ? cnt[idx] : 0;
        tsum += c[j];
    }
    ls[t] = tsum;
    __syncthreads();
    for (int off = 1; off < TPB; off <<= 1) {
        int v = (t >= off) ? ls[t - off] : 0;
        __syncthreads();
        ls[t] += v;
        __syncthreads();
    }
    int run = ls[t] - tsum;  // exclusive across threads in block
#pragma unroll
    for (int j = 0; j < 8; ++j) {
        int idx = base + j;
        if (idx < n) rp[idx] = run;
        run += c[j];
    }
    if (t == TPB - 1) bsum[b] = ls[TPB - 1];
}

// single-wave scan of block sums (nb <= 64 for N <= 131072)
__global__ void k_scan_sums(int* __restrict__ bsum, int* __restrict__ rp, int nb, int n) {
    int l = threadIdx.x;
    int v = (l < nb) ? bsum[l] : 0;
    int inc = v;
    for (int off = 1; off < 64; off <<= 1) {
        int u = __shfl_up(inc, off);
        if (l >= off) inc += u;
    }
    int tot = __shfl(inc, 63);
    if (l < nb) bsum[l] = inc - v;   // exclusive base
    if (l == 0) rp[n] = tot;
}

__global__ void k_scan_add(int* __restrict__ rp, const int* __restrict__ bsum,
                           int* __restrict__ pos, int n) {
    int b = blockIdx.x;
    int base_v = bsum[b];
    for (int i = threadIdx.x; i < 2048; i += TPB) {
        int idx = b * 2048 + i;
        if (idx < n) {
            int val = rp[idx] + base_v;
            rp[idx] = val;
            pos[idx] = val;
        }
    }
}

// fill CSR payload with SRC node id directly (saves a dependent load later)
__global__ void k_fill(const int* __restrict__ dst, const int* __restrict__ src,
                       int* __restrict__ pos, int* __restrict__ csrc, int e) {
    int i = blockIdx.x * TPB + threadIdx.x;
    if (i < e) {
        int d = dst[i];
        int p = atomicAdd(&pos[d], 1);
        csrc[p] = src[i];
    }
}

// ---------------- fused GEMM + el/er ----------------
// F[n,128] = maskedA @ W ; EL[n,h] = sum_d F[n,h,d]*al[h,d] ; ER likewise
template <int MASKED>
__global__ __launch_bounds__(TPB) void k_gemm_att(
    const float* __restrict__ A, const int* __restrict__ flag,
    const float* __restrict__ mtok, const float* __restrict__ W,
    const float* __restrict__ al, const float* __restrict__ ar,
    float* __restrict__ F, float* __restrict__ EL, float* __restrict__ ER, int n)
{
    __shared__ float sA[32][128];   // 16 KB
    __shared__ float sW[128][128];  // 64 KB
    int t = threadIdx.x;
    int bm0 = blockIdx.x * 32;
    for (int i = t; i < 4096; i += TPB)
        reinterpret_cast<float4*>(&sW[0][0])[i] = reinterpret_cast<const float4*>(W)[i];
    for (int i = t; i < 1024; i += TPB) {
        int r = i >> 5, c4 = i & 31;
        int row = bm0 + r;
        float4 v = make_float4(0.f, 0.f, 0.f, 0.f);
        if (row < n) {
            if (MASKED && flag[row]) v = reinterpret_cast<const float4*>(mtok)[c4];
            else v = reinterpret_cast<const float4*>(A + (size_t)row * 128)[c4];
        }
        reinterpret_cast<float4*>(&sA[r][0])[c4] = v;
    }
    __syncthreads();
    int lane = t & 63, wave = t >> 6;
    int half = lane >> 5;
    int c0 = (lane & 31) * 4;
    int r0 = wave * 8 + half * 4;
    float acc[4][4] = {};
#pragma unroll 8
    for (int k = 0; k < 128; ++k) {
        float4 wv = *reinterpret_cast<const float4*>(&sW[k][c0]);
#pragma unroll
        for (int r = 0; r < 4; ++r) {
            float a = sA[r0 + r][k];
            acc[r][0] += a * wv.x;
            acc[r][1] += a * wv.y;
            acc[r][2] += a * wv.z;
            acc[r][3] += a * wv.w;
        }
    }
    int h = (lane & 31) >> 3;      // head of this lane's 4 cols
    int cc = (lane & 7) * 4;       // col offset within head
    float4 alv = *reinterpret_cast<const float4*>(al + h * 32 + cc);
    float4 arv = *reinterpret_cast<const float4*>(ar + h * 32 + cc);
#pragma unroll
    for (int r = 0; r < 4; ++r) {
        int row = bm0 + r0 + r;
        if (row < n) {
            float4 o = make_float4(acc[r][0], acc[r][1], acc[r][2], acc[r][3]);
            *reinterpret_cast<float4*>(F + (size_t)row * 128 + c0) = o;
        }
        float pl = acc[r][0] * alv.x + acc[r][1] * alv.y + acc[r][2] * alv.z + acc[r][3] * alv.w;
        float pr = acc[r][0] * arv.x + acc[r][1] * arv.y + acc[r][2] * arv.z + acc[r][3] * arv.w;
        pl += __shfl_xor(pl, 1); pl += __shfl_xor(pl, 2); pl += __shfl_xor(pl, 4);
        pr += __shfl_xor(pr, 1); pr += __shfl_xor(pr, 2); pr += __shfl_xor(pr, 4);
        if ((lane & 7) == 0 && row < n) {
            EL[row * 4 + h] = pl;
            ER[row * 4 + h] = pr;
        }
    }
}

// ---------------- node-centric softmax + aggregate ----------------
// one wave per dst node; softmax over incoming edges (shift-invariant, no max pass)
__global__ __launch_bounds__(TPB) void k_node_agg(
    const float* __restrict__ F, const float* __restrict__ EL,
    const float* __restrict__ ER, const float* __restrict__ bias,
    const int* __restrict__ rp, const int* __restrict__ csrc,
    float* __restrict__ OUT, int n)
{
    int lane = threadIdx.x & 63;
    int v = blockIdx.x * 4 + (threadIdx.x >> 6);
    if (v >= n) return;
    int p0 = rp[v], p1 = rp[v + 1];
    int deg = p1 - p0;
    // phase A: per-head sum of exp over incoming edges; lane -> (edge=lane>>2, head=lane&3)
    int hA = lane & 3;
    float er_hA = ER[v * 4 + hA];
    float ssum = 0.f;
    for (int base = 0; base < deg; base += 16) {
        int i = base + (lane >> 2);
        float ex = 0.f;
        if (i < deg) {
            int s = csrc[p0 + i];
            ex = __expf(lrelu(EL[s * 4 + hA] + er_hA));
        }
        ssum += ex;
    }
    ssum += __shfl_xor(ssum, 4);
    ssum += __shfl_xor(ssum, 8);
    ssum += __shfl_xor(ssum, 16);
    ssum += __shfl_xor(ssum, 32);
    // phase B: feature-parallel aggregation; lane owns features 2l,2l+1, head = lane>>4
    int hB = lane >> 4;
    float s_h = __shfl(ssum, hB);
    float inv_s = s_h > 0.f ? 1.0f / s_h : 0.f;
    float er_hB = ER[v * 4 + hB];
    float acc0 = 0.f, acc1 = 0.f;
    for (int i = 0; i < deg; ++i) {
        int s = csrc[p0 + i];
        float pcoef = __expf(lrelu(EL[s * 4 + hB] + er_hB)) * inv_s;
        float2 fv = *reinterpret_cast<const float2*>(F + (size_t)s * 128 + lane * 2);
        acc0 += pcoef * fv.x;
        acc1 += pcoef * fv.y;
    }
    float2 bv = *reinterpret_cast<const float2*>(bias + lane * 2);
    float o0 = acc0 + bv.x; o0 = o0 > 0.f ? o0 : 0.f;
    float o1 = acc1 + bv.y; o1 = o1 > 0.f ? o1 : 0.f;
    *reinterpret_cast<float2*>(OUT + (size_t)v * 128 + lane * 2) = make_float2(o0, o1);
}

// ---------------- decoder GEMM on mask rows + squared-diff partial ----------------
__global__ __launch_bounds__(TPB) void k_loss(
    const float* __restrict__ H, const int* __restrict__ midx,
    const float* __restrict__ Wd, const float* __restrict__ bd,
    const float* __restrict__ attr, int m, float* __restrict__ part)
{
    __shared__ float sA[32][128];
    __shared__ float sW[128][128];
    __shared__ int srow[32];
    __shared__ float red[TPB];
    int t = threadIdx.x;
    int bm0 = blockIdx.x * 32;
    if (t < 32) {
        int i = bm0 + t;
        srow[t] = (i < m) ? midx[i] : -1;
    }
    for (int i = t; i < 4096; i += TPB)
        reinterpret_cast<float4*>(&sW[0][0])[i] = reinterpret_cast<const float4*>(Wd)[i];
    __syncthreads();
    for (int i = t; i < 1024; i += TPB) {
        int r = i >> 5, c4 = i & 31;
        int node = srow[r];
        float4 v = make_float4(0.f, 0.f, 0.f, 0.f);
        if (node >= 0) v = reinterpret_cast<const float4*>(H + (size_t)node * 128)[c4];
        reinterpret_cast<float4*>(&sA[r][0])[c4] = v;
    }
    __syncthreads();
    int lane = t & 63, wave = t >> 6;
    int half = lane >> 5;
    int c0 = (lane & 31) * 4;
    int r0 = wave * 8 + half * 4;
    float acc[4][4] = {};
#pragma unroll 8
    for (int k = 0; k < 128; ++k) {
        float4 wv = *reinterpret_cast<const float4*>(&sW[k][c0]);
#pragma unroll
        for (int r = 0; r < 4; ++r) {
            float a = sA[r0 + r][k];
            acc[r][0] += a * wv.x;
            acc[r][1] += a * wv.y;
            acc[r][2] += a * wv.z;
            acc[r][3] += a * wv.w;
        }
    }
    float local = 0.f;
    float4 bv = *reinterpret_cast<const float4*>(bd + c0);
#pragma unroll
    for (int r = 0; r < 4; ++r) {
        int i = bm0 + r0 + r;
        if (i < m) {
            int node = srow[r0 + r];
            float4 at = *reinterpret_cast<const float4*>(attr + (size_t)node * 128 + c0);
            float d0 = acc[r][0] + bv.x - at.x;
            float d1 = acc[r][1] + bv.y - at.y;
            float d2 = acc[r][2] + bv.z - at.z;
            float d3 = acc[r][3] + bv.w - at.w;
            local += d0 * d0 + d1 * d1 + d2 * d2 + d3 * d3;
        }
    }
    red[t] = local;
    __syncthreads();
    for (int off = TPB / 2; off > 0; off >>= 1) {
        if (t < off) red[t] += red[t + off];
        __syncthreads();
    }
    if (t == 0) part[blockIdx.x] = red[0];
}

__global__ void k_final(const float* __restrict__ part, int np, double inv_denom,
                        float* __restrict__ out)
{
    __shared__ double red[TPB];
    int t = threadIdx.x;
    double s = 0.0;
    for (int i = t; i < np; i += TPB) s += (double)part[i];
    red[t] = s;
    __syncthreads();
    for (int off = TPB / 2; off > 0; off >>= 1) {
        if (t < off) red[t] += red[t + off];
        __syncthreads();
    }
    if (t == 0) out[0] = (float)(red[0] * inv_denom);
}

// ---------------- launch ----------------
extern "C" void kernel_launch(void* const* d_in, const int* in_sizes, int n_in,
                              void* d_out, int out_size, void* d_ws, size_t ws_size,
                              hipStream_t stream)
{
    const float* attr = (const float*)d_in[0];
    const int*   src  = (const int*)d_in[1];
    const int*   dst  = (const int*)d_in[2];
    const int*   midx = (const int*)d_in[3];
    const float* W0   = (const float*)d_in[4];
    const float* al0  = (const float*)d_in[5];
    const float* ar0  = (const float*)d_in[6];
    const float* b0   = (const float*)d_in[7];
    const float* W1   = (const float*)d_in[8];
    const float* al1  = (const float*)d_in[9];
    const float* ar1  = (const float*)d_in[10];
    const float* b1   = (const float*)d_in[11];
    const float* Wd   = (const float*)d_in[12];
    const float* bd   = (const float*)d_in[13];
    const float* mtok = (const float*)d_in[14];

    int N = in_sizes[0] / 128;
    int E = in_sizes[1];
    int M = in_sizes[3];

    char* p = (char*)d_ws;
    auto carve = [&](size_t bytes) {
        char* q = p;
        p += (bytes + 255) & ~(size_t)255;
        return q;
    };
    float* f    = (float*)carve((size_t)N * 128 * 4);
    float* h    = (float*)carve((size_t)N * 128 * 4);
    float* el   = (float*)carve((size_t)N * 4 * 4);
    float* er   = (float*)carve((size_t)N * 4 * 4);
    int*   flag = (int*)carve((size_t)N * 4);
    int*   cnt  = (int*)carve((size_t)N * 4);
    int*   rp   = (int*)carve((size_t)(N + 1) * 4);
    int*   pos  = (int*)carve((size_t)N * 4);
    int*   csrc = (int*)carve((size_t)E * 4);
    int NB = (N + 2047) / 2048;
    int*   bsum = (int*)carve((size_t)NB * 4);
    int NLB = (M + 31) / 32;
    float* part = (float*)carve((size_t)NLB * 4);
    (void)ws_size; (void)n_in; (void)out_size;

    hipMemsetAsync(flag, 0, (size_t)N * 4, stream);
    hipMemsetAsync(cnt, 0, (size_t)N * 4, stream);

    k_setflag<<<(M + TPB - 1) / TPB, TPB, 0, stream>>>(midx, flag, M);
    k_count<<<(E + TPB - 1) / TPB, TPB, 0, stream>>>(dst, cnt, E);
    k_scan_block<<<NB, TPB, 0, stream>>>(cnt, rp, bsum, N);
    k_scan_sums<<<1, 64, 0, stream>>>(bsum, rp, NB, N);
    k_scan_add<<<NB, TPB, 0, stream>>>(rp, bsum, pos, N);
    k_fill<<<(E + TPB - 1) / TPB, TPB, 0, stream>>>(dst, src, pos, csrc, E);

    int GB = (N + 31) / 32;
    int NAB = (N + 3) / 4;
    // layer 0
    k_gemm_att<1><<<GB, TPB, 0, stream>>>(attr, flag, mtok, W0, al0, ar0, f, el, er, N);
    k_node_agg<<<NAB, TPB, 0, stream>>>(f, el, er, b0, rp, csrc, h, N);
    // layer 1
    k_gemm_att<0><<<GB, TPB, 0, stream>>>(h, nullptr, nullptr, W1, al1, ar1, f, el, er, N);
    k_node_agg<<<NAB, TPB, 0, stream>>>(f, el, er, b1, rp, csrc, h, N);
    // decoder + loss
    k_loss<<<NLB, TPB, 0, stream>>>(h, midx, Wd, bd, attr, M, part);
    k_final<<<1, TPB, 0, stream>>>(part, NLB, 1.0 / ((double)M * 128.0), (float*)d_out);
}

// Round 2
// 563.041 us; speedup vs baseline: 1.3801x; 1.3801x over previous
//
#include <hip/hip_runtime.h>
#include <cstdint>

#define TPB 256

__device__ __forceinline__ float lrelu(float x) { return x > 0.0f ? x : 0.2f * x; }

// round-to-nearest-even fp32 -> bf16 (finite values only)
__device__ __forceinline__ unsigned short f2bf(float x) {
    unsigned int u = __float_as_uint(x);
    unsigned int r = (u + 0x7FFFu + ((u >> 16) & 1u)) >> 16;
    return (unsigned short)r;
}
__device__ __forceinline__ float bf_lo(unsigned int u) { return __uint_as_float(u << 16); }
__device__ __forceinline__ float bf_hi(unsigned int u) { return __uint_as_float(u & 0xFFFF0000u); }

// ---------------- graph build ----------------
__global__ void k_setflag(const int* __restrict__ midx, int* __restrict__ flag, int m) {
    int i = blockIdx.x * TPB + threadIdx.x;
    if (i < m) flag[midx[i]] = 1;
}

__global__ void k_count(const int* __restrict__ dst, int* __restrict__ cnt, int e) {
    int i = blockIdx.x * TPB + threadIdx.x;
    if (i < e) atomicAdd(&cnt[dst[i]], 1);
}

// exclusive scan, 2048 elements per block
__global__ void k_scan_block(const int* __restrict__ cnt, int* __restrict__ rp,
                             int* __restrict__ bsum, int n) {
    __shared__ int ls[TPB];
    int t = threadIdx.x, b = blockIdx.x;
    int base = b * 2048 + t * 8;
    int c[8];
    int tsum = 0;
#pragma unroll
    for (int j = 0; j < 8; ++j) {
        int idx = base + j;
        c[j] = (idx < n) ? cnt[idx] : 0;
        tsum += c[j];
    }
    ls[t] = tsum;
    __syncthreads();
    for (int off = 1; off < TPB; off <<= 1) {
        int v = (t >= off) ? ls[t - off] : 0;
        __syncthreads();
        ls[t] += v;
        __syncthreads();
    }
    int run = ls[t] - tsum;  // exclusive across threads in block
#pragma unroll
    for (int j = 0; j < 8; ++j) {
        int idx = base + j;
        if (idx < n) rp[idx] = run;
        run += c[j];
    }
    if (t == TPB - 1) bsum[b] = ls[TPB - 1];
}

// single-wave scan of block sums (nb <= 64 for N <= 131072)
__global__ void k_scan_sums(int* __restrict__ bsum, int* __restrict__ rp, int nb, int n) {
    int l = threadIdx.x;
    int v = (l < nb) ? bsum[l] : 0;
    int inc = v;
    for (int off = 1; off < 64; off <<= 1) {
        int u = __shfl_up(inc, off);
        if (l >= off) inc += u;
    }
    int tot = __shfl(inc, 63);
    if (l < nb) bsum[l] = inc - v;   // exclusive base
    if (l == 0) rp[n] = tot;
}

__global__ void k_scan_add(int* __restrict__ rp, const int* __restrict__ bsum,
                           int* __restrict__ pos, int n) {
    int b = blockIdx.x;
    int base_v = bsum[b];
    for (int i = threadIdx.x; i < 2048; i += TPB) {
        int idx = b * 2048 + i;
        if (idx < n) {
            int val = rp[idx] + base_v;
            rp[idx] = val;
            pos[idx] = val;
        }
    }
}

// fill CSR payload with SRC node id directly
__global__ void k_fill(const int* __restrict__ dst, const int* __restrict__ src,
                       int* __restrict__ pos, int* __restrict__ csrc, int e) {
    int i = blockIdx.x * TPB + threadIdx.x;
    if (i < e) {
        int d = dst[i];
        int p = atomicAdd(&pos[d], 1);
        csrc[p] = src[i];
    }
}

// ---------------- fused GEMM + el/er, bf16 F output ----------------
template <int MASKED>
__global__ __launch_bounds__(TPB) void k_gemm_att(
    const float* __restrict__ A, const int* __restrict__ flag,
    const float* __restrict__ mtok, const float* __restrict__ W,
    const float* __restrict__ al, const float* __restrict__ ar,
    unsigned short* __restrict__ Fb, float* __restrict__ EL, float* __restrict__ ER, int n)
{
    __shared__ float sA[32][128];   // 16 KB
    __shared__ float sW[128][128];  // 64 KB
    int t = threadIdx.x;
    int bm0 = blockIdx.x * 32;
    for (int i = t; i < 4096; i += TPB)
        reinterpret_cast<float4*>(&sW[0][0])[i] = reinterpret_cast<const float4*>(W)[i];
    for (int i = t; i < 1024; i += TPB) {
        int r = i >> 5, c4 = i & 31;
        int row = bm0 + r;
        float4 v = make_float4(0.f, 0.f, 0.f, 0.f);
        if (row < n) {
            if (MASKED && flag[row]) v = reinterpret_cast<const float4*>(mtok)[c4];
            else v = reinterpret_cast<const float4*>(A + (size_t)row * 128)[c4];
        }
        reinterpret_cast<float4*>(&sA[r][0])[c4] = v;
    }
    __syncthreads();
    int lane = t & 63, wave = t >> 6;
    int half = lane >> 5;
    int c0 = (lane & 31) * 4;
    int r0 = wave * 8 + half * 4;
    float acc[4][4] = {};
#pragma unroll 8
    for (int k = 0; k < 128; ++k) {
        float4 wv = *reinterpret_cast<const float4*>(&sW[k][c0]);
#pragma unroll
        for (int r = 0; r < 4; ++r) {
            float a = sA[r0 + r][k];
            acc[r][0] += a * wv.x;
            acc[r][1] += a * wv.y;
            acc[r][2] += a * wv.z;
            acc[r][3] += a * wv.w;
        }
    }
    int h = (lane & 31) >> 3;      // head of this lane's 4 cols
    int cc = (lane & 7) * 4;       // col offset within head
    float4 alv = *reinterpret_cast<const float4*>(al + h * 32 + cc);
    float4 arv = *reinterpret_cast<const float4*>(ar + h * 32 + cc);
#pragma unroll
    for (int r = 0; r < 4; ++r) {
        int row = bm0 + r0 + r;
        if (row < n) {
            ushort4 o;
            o.x = f2bf(acc[r][0]); o.y = f2bf(acc[r][1]);
            o.z = f2bf(acc[r][2]); o.w = f2bf(acc[r][3]);
            *reinterpret_cast<ushort4*>(Fb + (size_t)row * 128 + c0) = o;
        }
        float pl = acc[r][0] * alv.x + acc[r][1] * alv.y + acc[r][2] * alv.z + acc[r][3] * alv.w;
        float pr = acc[r][0] * arv.x + acc[r][1] * arv.y + acc[r][2] * arv.z + acc[r][3] * arv.w;
        pl += __shfl_xor(pl, 1); pl += __shfl_xor(pl, 2); pl += __shfl_xor(pl, 4);
        pr += __shfl_xor(pr, 1); pr += __shfl_xor(pr, 2); pr += __shfl_xor(pr, 4);
        if ((lane & 7) == 0 && row < n) {
            EL[row * 4 + h] = pl;
            ER[row * 4 + h] = pr;
        }
    }
}

// ---------------- node-centric softmax + aggregate, single pass ----------------
// one wave per dst node; unnormalized accumulate, divide at the end.
// lane owns features 2l,2l+1 (one packed bf16x2 word); head = lane>>4.
__global__ __launch_bounds__(TPB) void k_node_agg(
    const unsigned int* __restrict__ Fu,   // bf16 [N][128] viewed as uint[N][64]
    const float* __restrict__ EL, const float* __restrict__ ER,
    const float* __restrict__ bias,
    const int* __restrict__ rp, const int* __restrict__ csrc,
    float* __restrict__ OUT, int n)
{
    int lane = threadIdx.x & 63;
    int v = blockIdx.x * 4 + (threadIdx.x >> 6);
    if (v >= n) return;
    int p0 = rp[v], p1 = rp[v + 1];
    int deg = p1 - p0;
    int h = lane >> 4;
    float er_h = ER[v * 4 + h];
    float acc0 = 0.f, acc1 = 0.f, ssum = 0.f;
    int i = 0;
    for (; i + 4 <= deg; i += 4) {
        int s0 = csrc[p0 + i];
        int s1 = csrc[p0 + i + 1];
        int s2 = csrc[p0 + i + 2];
        int s3 = csrc[p0 + i + 3];
        float e0 = EL[s0 * 4 + h];
        float e1 = EL[s1 * 4 + h];
        float e2 = EL[s2 * 4 + h];
        float e3 = EL[s3 * 4 + h];
        unsigned int u0 = Fu[(size_t)s0 * 64 + lane];
        unsigned int u1 = Fu[(size_t)s1 * 64 + lane];
        unsigned int u2 = Fu[(size_t)s2 * 64 + lane];
        unsigned int u3 = Fu[(size_t)s3 * 64 + lane];
        float x0 = __expf(lrelu(e0 + er_h));
        float x1 = __expf(lrelu(e1 + er_h));
        float x2 = __expf(lrelu(e2 + er_h));
        float x3 = __expf(lrelu(e3 + er_h));
        ssum += x0 + x1 + x2 + x3;
        acc0 += x0 * bf_lo(u0); acc1 += x0 * bf_hi(u0);
        acc0 += x1 * bf_lo(u1); acc1 += x1 * bf_hi(u1);
        acc0 += x2 * bf_lo(u2); acc1 += x2 * bf_hi(u2);
        acc0 += x3 * bf_lo(u3); acc1 += x3 * bf_hi(u3);
    }
    for (; i < deg; ++i) {
        int s = csrc[p0 + i];
        float x = __expf(lrelu(EL[s * 4 + h] + er_h));
        unsigned int u = Fu[(size_t)s * 64 + lane];
        ssum += x;
        acc0 += x * bf_lo(u);
        acc1 += x * bf_hi(u);
    }
    float inv_s = ssum > 0.f ? 1.0f / ssum : 0.f;
    float2 bv = *reinterpret_cast<const float2*>(bias + lane * 2);
    float o0 = acc0 * inv_s + bv.x; o0 = o0 > 0.f ? o0 : 0.f;
    float o1 = acc1 * inv_s + bv.y; o1 = o1 > 0.f ? o1 : 0.f;
    *reinterpret_cast<float2*>(OUT + (size_t)v * 128 + lane * 2) = make_float2(o0, o1);
}

// ---------------- decoder GEMM on mask rows + squared-diff partial ----------------
__global__ __launch_bounds__(TPB) void k_loss(
    const float* __restrict__ H, const int* __restrict__ midx,
    const float* __restrict__ Wd, const float* __restrict__ bd,
    const float* __restrict__ attr, int m, float* __restrict__ part)
{
    __shared__ float sA[32][128];
    __shared__ float sW[128][128];
    __shared__ int srow[32];
    __shared__ float red[TPB];
    int t = threadIdx.x;
    int bm0 = blockIdx.x * 32;
    if (t < 32) {
        int i = bm0 + t;
        srow[t] = (i < m) ? midx[i] : -1;
    }
    for (int i = t; i < 4096; i += TPB)
        reinterpret_cast<float4*>(&sW[0][0])[i] = reinterpret_cast<const float4*>(Wd)[i];
    __syncthreads();
    for (int i = t; i < 1024; i += TPB) {
        int r = i >> 5, c4 = i & 31;
        int node = srow[r];
        float4 v = make_float4(0.f, 0.f, 0.f, 0.f);
        if (node >= 0) v = reinterpret_cast<const float4*>(H + (size_t)node * 128)[c4];
        reinterpret_cast<float4*>(&sA[r][0])[c4] = v;
    }
    __syncthreads();
    int lane = t & 63, wave = t >> 6;
    int half = lane >> 5;
    int c0 = (lane & 31) * 4;
    int r0 = wave * 8 + half * 4;
    float acc[4][4] = {};
#pragma unroll 8
    for (int k = 0; k < 128; ++k) {
        float4 wv = *reinterpret_cast<const float4*>(&sW[k][c0]);
#pragma unroll
        for (int r = 0; r < 4; ++r) {
            float a = sA[r0 + r][k];
            acc[r][0] += a * wv.x;
            acc[r][1] += a * wv.y;
            acc[r][2] += a * wv.z;
            acc[r][3] += a * wv.w;
        }
    }
    float local = 0.f;
    float4 bv = *reinterpret_cast<const float4*>(bd + c0);
#pragma unroll
    for (int r = 0; r < 4; ++r) {
        int i = bm0 + r0 + r;
        if (i < m) {
            int node = srow[r0 + r];
            float4 at = *reinterpret_cast<const float4*>(attr + (size_t)node * 128 + c0);
            float d0 = acc[r][0] + bv.x - at.x;
            float d1 = acc[r][1] + bv.y - at.y;
            float d2 = acc[r][2] + bv.z - at.z;
            float d3 = acc[r][3] + bv.w - at.w;
            local += d0 * d0 + d1 * d1 + d2 * d2 + d3 * d3;
        }
    }
    red[t] = local;
    __syncthreads();
    for (int off = TPB / 2; off > 0; off >>= 1) {
        if (t < off) red[t] += red[t + off];
        __syncthreads();
    }
    if (t == 0) part[blockIdx.x] = red[0];
}

__global__ void k_final(const float* __restrict__ part, int np, double inv_denom,
                        float* __restrict__ out)
{
    __shared__ double red[TPB];
    int t = threadIdx.x;
    double s = 0.0;
    for (int i = t; i < np; i += TPB) s += (double)part[i];
    red[t] = s;
    __syncthreads();
    for (int off = TPB / 2; off > 0; off >>= 1) {
        if (t < off) red[t] += red[t + off];
        __syncthreads();
    }
    if (t == 0) out[0] = (float)(red[0] * inv_denom);
}

// ---------------- launch ----------------
extern "C" void kernel_launch(void* const* d_in, const int* in_sizes, int n_in,
                              void* d_out, int out_size, void* d_ws, size_t ws_size,
                              hipStream_t stream)
{
    const float* attr = (const float*)d_in[0];
    const int*   src  = (const int*)d_in[1];
    const int*   dst  = (const int*)d_in[2];
    const int*   midx = (const int*)d_in[3];
    const float* W0   = (const float*)d_in[4];
    const float* al0  = (const float*)d_in[5];
    const float* ar0  = (const float*)d_in[6];
    const float* b0   = (const float*)d_in[7];
    const float* W1   = (const float*)d_in[8];
    const float* al1  = (const float*)d_in[9];
    const float* ar1  = (const float*)d_in[10];
    const float* b1   = (const float*)d_in[11];
    const float* Wd   = (const float*)d_in[12];
    const float* bd   = (const float*)d_in[13];
    const float* mtok = (const float*)d_in[14];

    int N = in_sizes[0] / 128;
    int E = in_sizes[1];
    int M = in_sizes[3];

    char* p = (char*)d_ws;
    auto carve = [&](size_t bytes) {
        char* q = p;
        p += (bytes + 255) & ~(size_t)255;
        return q;
    };
    unsigned short* fb = (unsigned short*)carve((size_t)N * 128 * 2);  // bf16 F
    float* h    = (float*)carve((size_t)N * 128 * 4);
    float* el   = (float*)carve((size_t)N * 4 * 4);
    float* er   = (float*)carve((size_t)N * 4 * 4);
    int*   flag = (int*)carve((size_t)N * 4);
    int*   cnt  = (int*)carve((size_t)N * 4);
    int*   rp   = (int*)carve((size_t)(N + 1) * 4);
    int*   pos  = (int*)carve((size_t)N * 4);
    int*   csrc = (int*)carve((size_t)E * 4);
    int NB = (N + 2047) / 2048;
    int*   bsum = (int*)carve((size_t)NB * 4);
    int NLB = (M + 31) / 32;
    float* part = (float*)carve((size_t)NLB * 4);
    (void)ws_size; (void)n_in; (void)out_size;

    hipMemsetAsync(flag, 0, (size_t)N * 4, stream);
    hipMemsetAsync(cnt, 0, (size_t)N * 4, stream);

    k_setflag<<<(M + TPB - 1) / TPB, TPB, 0, stream>>>(midx, flag, M);
    k_count<<<(E + TPB - 1) / TPB, TPB, 0, stream>>>(dst, cnt, E);
    k_scan_block<<<NB, TPB, 0, stream>>>(cnt, rp, bsum, N);
    k_scan_sums<<<1, 64, 0, stream>>>(bsum, rp, NB, N);
    k_scan_add<<<NB, TPB, 0, stream>>>(rp, bsum, pos, N);
    k_fill<<<(E + TPB - 1) / TPB, TPB, 0, stream>>>(dst, src, pos, csrc, E);

    int GB = (N + 31) / 32;
    int NAB = (N + 3) / 4;
    // layer 0
    k_gemm_att<1><<<GB, TPB, 0, stream>>>(attr, flag, mtok, W0, al0, ar0, fb, el, er, N);
    k_node_agg<<<NAB, TPB, 0, stream>>>((const unsigned int*)fb, el, er, b0, rp, csrc, h, N);
    // layer 1
    k_gemm_att<0><<<GB, TPB, 0, stream>>>(h, nullptr, nullptr, W1, al1, ar1, fb, el, er, N);
    k_node_agg<<<NAB, TPB, 0, stream>>>((const unsigned int*)fb, el, er, b1, rp, csrc, h, N);
    // decoder + loss
    k_loss<<<NLB, TPB, 0, stream>>>(h, midx, Wd, bd, attr, M, part);
    k_final<<<1, TPB, 0, stream>>>(part, NLB, 1.0 / ((double)M * 128.0), (float*)d_out);
}

// Round 3
// 387.608 us; speedup vs baseline: 2.0048x; 1.4526x over previous
//
#include <hip/hip_runtime.h>
#include <cstdint>

#define TPB 256

typedef __attribute__((ext_vector_type(8))) short short8_t;   // 8 bf16
typedef __attribute__((ext_vector_type(4))) float f32x4;

__device__ __forceinline__ float lrelu(float x) { return x > 0.0f ? x : 0.2f * x; }

// round-to-nearest-even fp32 -> bf16
__device__ __forceinline__ unsigned short f2bf(float x) {
    unsigned int u = __float_as_uint(x);
    unsigned int r = (u + 0x7FFFu + ((u >> 16) & 1u)) >> 16;
    return (unsigned short)r;
}
__device__ __forceinline__ float bf_lo(unsigned int u) { return __uint_as_float(u << 16); }
__device__ __forceinline__ float bf_hi(unsigned int u) { return __uint_as_float(u & 0xFFFF0000u); }

// ---------------- graph build ----------------
__global__ void k_setflag(const int* __restrict__ midx, int* __restrict__ flag, int m) {
    int i = blockIdx.x * TPB + threadIdx.x;
    if (i < m) flag[midx[i]] = 1;
}

// count + per-edge rank (atomic return), rank write is coalesced
__global__ void k_count_rank(const int* __restrict__ dst, int* __restrict__ cnt,
                             int* __restrict__ rank, int e) {
    int i = blockIdx.x * TPB + threadIdx.x;
    if (i < e) rank[i] = atomicAdd(&cnt[dst[i]], 1);
}

// exclusive scan, 2048 elements per block
__global__ void k_scan_block(const int* __restrict__ cnt, int* __restrict__ rp,
                             int* __restrict__ bsum, int n) {
    __shared__ int ls[TPB];
    int t = threadIdx.x, b = blockIdx.x;
    int base = b * 2048 + t * 8;
    int c[8];
    int tsum = 0;
#pragma unroll
    for (int j = 0; j < 8; ++j) {
        int idx = base + j;
        c[j] = (idx < n) ? cnt[idx] : 0;
        tsum += c[j];
    }
    ls[t] = tsum;
    __syncthreads();
    for (int off = 1; off < TPB; off <<= 1) {
        int v = (t >= off) ? ls[t - off] : 0;
        __syncthreads();
        ls[t] += v;
        __syncthreads();
    }
    int run = ls[t] - tsum;
#pragma unroll
    for (int j = 0; j < 8; ++j) {
        int idx = base + j;
        if (idx < n) rp[idx] = run;
        run += c[j];
    }
    if (t == TPB - 1) bsum[b] = ls[TPB - 1];
}

__global__ void k_scan_sums(int* __restrict__ bsum, int* __restrict__ rp, int nb, int n) {
    int l = threadIdx.x;
    int v = (l < nb) ? bsum[l] : 0;
    int inc = v;
    for (int off = 1; off < 64; off <<= 1) {
        int u = __shfl_up(inc, off);
        if (l >= off) inc += u;
    }
    int tot = __shfl(inc, 63);
    if (l < nb) bsum[l] = inc - v;
    if (l == 0) rp[n] = tot;
}

__global__ void k_scan_add(int* __restrict__ rp, const int* __restrict__ bsum, int n) {
    int b = blockIdx.x;
    int base_v = bsum[b];
    for (int i = threadIdx.x; i < 2048; i += TPB) {
        int idx = b * 2048 + i;
        if (idx < n) rp[idx] += base_v;
    }
}

// pure scatter, no atomic
__global__ void k_fill(const int* __restrict__ dst, const int* __restrict__ src,
                       const int* __restrict__ rank, const int* __restrict__ rp,
                       int* __restrict__ csrc, int e) {
    int i = blockIdx.x * TPB + threadIdx.x;
    if (i < e) csrc[rp[dst[i]] + rank[i]] = src[i];
}

// ---------------- W -> B-fragment pack (bf16) ----------------
// Bpack[kb][n][i] = bf16(W[kb*8+i][n]), kb in [0,16), n in [0,128), i in [0,8)
__global__ void k_packW(const float* __restrict__ W, unsigned short* __restrict__ Bp) {
    int t = blockIdx.x * TPB + threadIdx.x;
    if (t >= 2048) return;
    int kb = t >> 7, n = t & 127;
    unsigned int w[4];
#pragma unroll
    for (int j = 0; j < 4; ++j) {
        unsigned int lo = f2bf(W[(kb * 8 + 2 * j) * 128 + n]);
        unsigned int hi = f2bf(W[(kb * 8 + 2 * j + 1) * 128 + n]);
        w[j] = lo | (hi << 16);
    }
    uint4 o = make_uint4(w[0], w[1], w[2], w[3]);
    reinterpret_cast<uint4*>(Bp)[t] = o;
}

// ---------------- MFMA bf16 GEMM: Fb[n,128] = bf16( maskedA @ W ) ----------------
// block tile: 128 rows x 128 cols, 4 waves, each wave 32 rows (2 m-frags) x 8 n-frags
template <int MASKED>
__global__ __launch_bounds__(TPB) void k_gemm_mfma(
    const float* __restrict__ A, const int* __restrict__ flag,
    const float* __restrict__ mtok, const unsigned short* __restrict__ Bpack,
    unsigned short* __restrict__ Fb, int n)
{
    __shared__ char sAb[32768];            // bf16 [128][128], XOR-swizzled rows
    __shared__ unsigned short sB[16384];   // Bpack copy, linear
    int t = threadIdx.x;
    int bm0 = blockIdx.x * 128;

    for (int i = t; i < 2048; i += TPB)
        reinterpret_cast<uint4*>(sB)[i] = reinterpret_cast<const uint4*>(Bpack)[i];

    // stage A (fp32 -> bf16), 128 rows x 32 float4, swizzle byte ^= (row&7)<<4
    for (int i = t; i < 4096; i += TPB) {
        int r = i >> 5, c4 = i & 31;
        int row = bm0 + r;
        float4 v = make_float4(0.f, 0.f, 0.f, 0.f);
        if (row < n) {
            if (MASKED && flag[row]) v = reinterpret_cast<const float4*>(mtok)[c4];
            else v = reinterpret_cast<const float4*>(A + (size_t)row * 128)[c4];
        }
        ushort4 o;
        o.x = f2bf(v.x); o.y = f2bf(v.y); o.z = f2bf(v.z); o.w = f2bf(v.w);
        int byte = r * 256 + ((c4 * 8) ^ ((r & 7) << 4));
        *reinterpret_cast<ushort4*>(sAb + byte) = o;
    }
    __syncthreads();

    int w = t >> 6, l = t & 63;
    int lm = l & 15, lg = l >> 4;
    const short8_t* bp = reinterpret_cast<const short8_t*>(sB);

    f32x4 acc[2][8];
#pragma unroll
    for (int mf = 0; mf < 2; ++mf)
#pragma unroll
        for (int f = 0; f < 8; ++f)
            acc[mf][f] = (f32x4){0.f, 0.f, 0.f, 0.f};

#pragma unroll
    for (int ks = 0; ks < 4; ++ks) {
        short8_t af[2];
#pragma unroll
        for (int mf = 0; mf < 2; ++mf) {
            int row = w * 32 + mf * 16 + lm;
            int byte = row * 256 + ((ks * 64 + lg * 16) ^ ((row & 7) << 4));
            af[mf] = *reinterpret_cast<const short8_t*>(sAb + byte);
        }
        int kb = ks * 4 + lg;
#pragma unroll
        for (int f = 0; f < 8; ++f) {
            short8_t bfr = bp[kb * 128 + f * 16 + lm];
            acc[0][f] = __builtin_amdgcn_mfma_f32_16x16x32_bf16(af[0], bfr, acc[0][f], 0, 0, 0);
            acc[1][f] = __builtin_amdgcn_mfma_f32_16x16x32_bf16(af[1], bfr, acc[1][f], 0, 0, 0);
        }
    }

    // D layout: row = (lane>>4)*4 + reg, col = lane&15
#pragma unroll
    for (int mf = 0; mf < 2; ++mf)
#pragma unroll
        for (int f = 0; f < 8; ++f)
#pragma unroll
            for (int r = 0; r < 4; ++r) {
                int row = bm0 + w * 32 + mf * 16 + lg * 4 + r;
                if (row < n) Fb[(size_t)row * 128 + f * 16 + lm] = f2bf(acc[mf][f][r]);
            }
}

// ---------------- el/er from bf16 F ----------------
// wave handles 8 rows; lane -> row = l>>3, 16 cols at (l&7)*16; head = (l&7)>>1
__global__ __launch_bounds__(TPB) void k_elr(
    const unsigned short* __restrict__ Fb, const float* __restrict__ al,
    const float* __restrict__ ar, float* __restrict__ EL, float* __restrict__ ER, int n)
{
    int l = threadIdx.x & 63;
    int wid = blockIdx.x * 4 + (threadIdx.x >> 6);
    int row = wid * 8 + (l >> 3);
    if (row >= n) return;
    int c0 = (l & 7) * 16;
    int head = (l & 7) >> 1;
    int hb = ((l & 7) & 1) * 16;
    const uint4* fq = reinterpret_cast<const uint4*>(Fb + (size_t)row * 128 + c0);
    uint4 u01 = fq[0], u23 = fq[1];
    unsigned int ua[8] = {u01.x, u01.y, u01.z, u01.w, u23.x, u23.y, u23.z, u23.w};
    const float* alp = al + head * 32 + hb;
    const float* arp = ar + head * 32 + hb;
    float el = 0.f, er = 0.f;
#pragma unroll
    for (int j = 0; j < 8; ++j) {
        float f0 = bf_lo(ua[j]), f1 = bf_hi(ua[j]);
        el += f0 * alp[2 * j] + f1 * alp[2 * j + 1];
        er += f0 * arp[2 * j] + f1 * arp[2 * j + 1];
    }
    el += __shfl_xor(el, 1);
    er += __shfl_xor(er, 1);
    if (((l & 7) & 1) == 0) {
        EL[row * 4 + head] = el;
        ER[row * 4 + head] = er;
    }
}

// ---------------- node-centric softmax + aggregate ----------------
__global__ __launch_bounds__(TPB) void k_node_agg(
    const unsigned int* __restrict__ Fu,
    const float* __restrict__ EL, const float* __restrict__ ER,
    const float* __restrict__ bias,
    const int* __restrict__ rp, const int* __restrict__ csrc,
    float* __restrict__ OUT, int n)
{
    int lane = threadIdx.x & 63;
    int v = blockIdx.x * 4 + (threadIdx.x >> 6);
    if (v >= n) return;
    int p0 = rp[v], p1 = rp[v + 1];
    int deg = p1 - p0;
    int h = lane >> 4;
    float er_h = ER[v * 4 + h];
    float acc0 = 0.f, acc1 = 0.f, ssum = 0.f;
    for (int base = 0; base < deg; base += 64) {
        int m = deg - base; if (m > 64) m = 64;
        int sreg = (base + lane < deg) ? csrc[p0 + base + lane] : 0;
        int j = 0;
        for (; j + 4 <= m; j += 4) {
            int s0 = __shfl(sreg, j);
            int s1 = __shfl(sreg, j + 1);
            int s2 = __shfl(sreg, j + 2);
            int s3 = __shfl(sreg, j + 3);
            float e0 = EL[s0 * 4 + h];
            float e1 = EL[s1 * 4 + h];
            float e2 = EL[s2 * 4 + h];
            float e3 = EL[s3 * 4 + h];
            unsigned int u0 = Fu[(size_t)s0 * 64 + lane];
            unsigned int u1 = Fu[(size_t)s1 * 64 + lane];
            unsigned int u2 = Fu[(size_t)s2 * 64 + lane];
            unsigned int u3 = Fu[(size_t)s3 * 64 + lane];
            float x0 = __expf(lrelu(e0 + er_h));
            float x1 = __expf(lrelu(e1 + er_h));
            float x2 = __expf(lrelu(e2 + er_h));
            float x3 = __expf(lrelu(e3 + er_h));
            ssum += x0 + x1 + x2 + x3;
            acc0 += x0 * bf_lo(u0); acc1 += x0 * bf_hi(u0);
            acc0 += x1 * bf_lo(u1); acc1 += x1 * bf_hi(u1);
            acc0 += x2 * bf_lo(u2); acc1 += x2 * bf_hi(u2);
            acc0 += x3 * bf_lo(u3); acc1 += x3 * bf_hi(u3);
        }
        for (; j < m; ++j) {
            int s = __shfl(sreg, j);
            float x = __expf(lrelu(EL[s * 4 + h] + er_h));
            unsigned int u = Fu[(size_t)s * 64 + lane];
            ssum += x;
            acc0 += x * bf_lo(u);
            acc1 += x * bf_hi(u);
        }
    }
    float inv_s = ssum > 0.f ? 1.0f / ssum : 0.f;
    float2 bv = *reinterpret_cast<const float2*>(bias + lane * 2);
    float o0 = acc0 * inv_s + bv.x; o0 = o0 > 0.f ? o0 : 0.f;
    float o1 = acc1 * inv_s + bv.y; o1 = o1 > 0.f ? o1 : 0.f;
    *reinterpret_cast<float2*>(OUT + (size_t)v * 128 + lane * 2) = make_float2(o0, o1);
}

// ---------------- decoder GEMM on mask rows + squared-diff partial ----------------
__global__ __launch_bounds__(TPB) void k_loss(
    const float* __restrict__ H, const int* __restrict__ midx,
    const float* __restrict__ Wd, const float* __restrict__ bd,
    const float* __restrict__ attr, int m, float* __restrict__ part)
{
    __shared__ float sA[32][128];
    __shared__ float sW[128][128];
    __shared__ int srow[32];
    __shared__ float red[TPB];
    int t = threadIdx.x;
    int bm0 = blockIdx.x * 32;
    if (t < 32) {
        int i = bm0 + t;
        srow[t] = (i < m) ? midx[i] : -1;
    }
    for (int i = t; i < 4096; i += TPB)
        reinterpret_cast<float4*>(&sW[0][0])[i] = reinterpret_cast<const float4*>(Wd)[i];
    __syncthreads();
    for (int i = t; i < 1024; i += TPB) {
        int r = i >> 5, c4 = i & 31;
        int node = srow[r];
        float4 v = make_float4(0.f, 0.f, 0.f, 0.f);
        if (node >= 0) v = reinterpret_cast<const float4*>(H + (size_t)node * 128)[c4];
        reinterpret_cast<float4*>(&sA[r][0])[c4] = v;
    }
    __syncthreads();
    int lane = t & 63, wave = t >> 6;
    int half = lane >> 5;
    int c0 = (lane & 31) * 4;
    int r0 = wave * 8 + half * 4;
    float acc[4][4] = {};
#pragma unroll 8
    for (int k = 0; k < 128; ++k) {
        float4 wv = *reinterpret_cast<const float4*>(&sW[k][c0]);
#pragma unroll
        for (int r = 0; r < 4; ++r) {
            float a = sA[r0 + r][k];
            acc[r][0] += a * wv.x;
            acc[r][1] += a * wv.y;
            acc[r][2] += a * wv.z;
            acc[r][3] += a * wv.w;
        }
    }
    float local = 0.f;
    float4 bv = *reinterpret_cast<const float4*>(bd + c0);
#pragma unroll
    for (int r = 0; r < 4; ++r) {
        int i = bm0 + r0 + r;
        if (i < m) {
            int node = srow[r0 + r];
            float4 at = *reinterpret_cast<const float4*>(attr + (size_t)node * 128 + c0);
            float d0 = acc[r][0] + bv.x - at.x;
            float d1 = acc[r][1] + bv.y - at.y;
            float d2 = acc[r][2] + bv.z - at.z;
            float d3 = acc[r][3] + bv.w - at.w;
            local += d0 * d0 + d1 * d1 + d2 * d2 + d3 * d3;
        }
    }
    red[t] = local;
    __syncthreads();
    for (int off = TPB / 2; off > 0; off >>= 1) {
        if (t < off) red[t] += red[t + off];
        __syncthreads();
    }
    if (t == 0) part[blockIdx.x] = red[0];
}

__global__ void k_final(const float* __restrict__ part, int np, double inv_denom,
                        float* __restrict__ out)
{
    __shared__ double red[TPB];
    int t = threadIdx.x;
    double s = 0.0;
    for (int i = t; i < np; i += TPB) s += (double)part[i];
    red[t] = s;
    __syncthreads();
    for (int off = TPB / 2; off > 0; off >>= 1) {
        if (t < off) red[t] += red[t + off];
        __syncthreads();
    }
    if (t == 0) out[0] = (float)(red[0] * inv_denom);
}

// ---------------- launch ----------------
extern "C" void kernel_launch(void* const* d_in, const int* in_sizes, int n_in,
                              void* d_out, int out_size, void* d_ws, size_t ws_size,
                              hipStream_t stream)
{
    const float* attr = (const float*)d_in[0];
    const int*   src  = (const int*)d_in[1];
    const int*   dst  = (const int*)d_in[2];
    const int*   midx = (const int*)d_in[3];
    const float* W0   = (const float*)d_in[4];
    const float* al0  = (const float*)d_in[5];
    const float* ar0  = (const float*)d_in[6];
    const float* b0   = (const float*)d_in[7];
    const float* W1   = (const float*)d_in[8];
    const float* al1  = (const float*)d_in[9];
    const float* ar1  = (const float*)d_in[10];
    const float* b1   = (const float*)d_in[11];
    const float* Wd   = (const float*)d_in[12];
    const float* bd   = (const float*)d_in[13];
    const float* mtok = (const float*)d_in[14];

    int N = in_sizes[0] / 128;
    int E = in_sizes[1];
    int M = in_sizes[3];

    char* p = (char*)d_ws;
    auto carve = [&](size_t bytes) {
        char* q = p;
        p += (bytes + 255) & ~(size_t)255;
        return q;
    };
    unsigned short* fb  = (unsigned short*)carve((size_t)N * 128 * 2);  // bf16 F
    float* h    = (float*)carve((size_t)N * 128 * 4);
    float* el   = (float*)carve((size_t)N * 4 * 4);
    float* er   = (float*)carve((size_t)N * 4 * 4);
    int*   flag = (int*)carve((size_t)N * 4);
    int*   cnt  = (int*)carve((size_t)N * 4);
    int*   rp   = (int*)carve((size_t)(N + 1) * 4);
    int*   rank = (int*)carve((size_t)E * 4);
    int*   csrc = (int*)carve((size_t)E * 4);
    unsigned short* bp0 = (unsigned short*)carve(16 * 128 * 8 * 2);
    unsigned short* bp1 = (unsigned short*)carve(16 * 128 * 8 * 2);
    int NB = (N + 2047) / 2048;
    int*   bsum = (int*)carve((size_t)NB * 4);
    int NLB = (M + 31) / 32;
    float* part = (float*)carve((size_t)NLB * 4);
    (void)ws_size; (void)n_in; (void)out_size;

    hipMemsetAsync(flag, 0, (size_t)N * 4, stream);
    hipMemsetAsync(cnt, 0, (size_t)N * 4, stream);

    k_setflag<<<(M + TPB - 1) / TPB, TPB, 0, stream>>>(midx, flag, M);
    k_count_rank<<<(E + TPB - 1) / TPB, TPB, 0, stream>>>(dst, cnt, rank, E);
    k_scan_block<<<NB, TPB, 0, stream>>>(cnt, rp, bsum, N);
    k_scan_sums<<<1, 64, 0, stream>>>(bsum, rp, NB, N);
    k_scan_add<<<NB, TPB, 0, stream>>>(rp, bsum, N);
    k_fill<<<(E + TPB - 1) / TPB, TPB, 0, stream>>>(dst, src, rank, rp, csrc, E);
    k_packW<<<8, TPB, 0, stream>>>(W0, bp0);
    k_packW<<<8, TPB, 0, stream>>>(W1, bp1);

    int GB = (N + 127) / 128;
    int EB = (N + 31) / 32;
    int NAB = (N + 3) / 4;
    // layer 0
    k_gemm_mfma<1><<<GB, TPB, 0, stream>>>(attr, flag, mtok, bp0, fb, N);
    k_elr<<<EB, TPB, 0, stream>>>(fb, al0, ar0, el, er, N);
    k_node_agg<<<NAB, TPB, 0, stream>>>((const unsigned int*)fb, el, er, b0, rp, csrc, h, N);
    // layer 1
    k_gemm_mfma<0><<<GB, TPB, 0, stream>>>(h, nullptr, nullptr, bp1, fb, N);
    k_elr<<<EB, TPB, 0, stream>>>(fb, al1, ar1, el, er, N);
    k_node_agg<<<NAB, TPB, 0, stream>>>((const unsigned int*)fb, el, er, b1, rp, csrc, h, N);
    // decoder + loss
    k_loss<<<NLB, TPB, 0, stream>>>(h, midx, Wd, bd, attr, M, part);
    k_final<<<1, TPB, 0, stream>>>(part, NLB, 1.0 / ((double)M * 128.0), (float*)d_out);
}

// Round 5
// 382.716 us; speedup vs baseline: 2.0304x; 1.0128x over previous
//
#include <hip/hip_runtime.h>
#include <cstdint>

#define TPB 256

typedef __attribute__((ext_vector_type(8))) short short8_t;   // 8 bf16
typedef __attribute__((ext_vector_type(4))) float f32x4;

__device__ __forceinline__ float lrelu(float x) { return x > 0.0f ? x : 0.2f * x; }

// round-to-nearest-even fp32 -> bf16
__device__ __forceinline__ unsigned short f2bf(float x) {
    unsigned int u = __float_as_uint(x);
    unsigned int r = (u + 0x7FFFu + ((u >> 16) & 1u)) >> 16;
    return (unsigned short)r;
}
__device__ __forceinline__ float bf_lo(unsigned int u) { return __uint_as_float(u << 16); }
__device__ __forceinline__ float bf_hi(unsigned int u) { return __uint_as_float(u & 0xFFFF0000u); }

// ---------------- graph build ----------------
__global__ void k_setflag(const int* __restrict__ midx, int* __restrict__ flag, int m) {
    int i = blockIdx.x * TPB + threadIdx.x;
    if (i < m) flag[midx[i]] = 1;
}

__global__ void k_count_rank(const int* __restrict__ dst, int* __restrict__ cnt,
                             int* __restrict__ rank, int e) {
    int i = blockIdx.x * TPB + threadIdx.x;
    if (i < e) rank[i] = atomicAdd(&cnt[dst[i]], 1);
}

__global__ void k_scan_block(const int* __restrict__ cnt, int* __restrict__ rp,
                             int* __restrict__ bsum, int n) {
    __shared__ int ls[TPB];
    int t = threadIdx.x, b = blockIdx.x;
    int base = b * 2048 + t * 8;
    int c[8];
    int tsum = 0;
#pragma unroll
    for (int j = 0; j < 8; ++j) {
        int idx = base + j;
        c[j] = (idx < n) ? cnt[idx] : 0;
        tsum += c[j];
    }
    ls[t] = tsum;
    __syncthreads();
    for (int off = 1; off < TPB; off <<= 1) {
        int v = (t >= off) ? ls[t - off] : 0;
        __syncthreads();
        ls[t] += v;
        __syncthreads();
    }
    int run = ls[t] - tsum;
#pragma unroll
    for (int j = 0; j < 8; ++j) {
        int idx = base + j;
        if (idx < n) rp[idx] = run;
        run += c[j];
    }
    if (t == TPB - 1) bsum[b] = ls[TPB - 1];
}

__global__ void k_scan_sums(int* __restrict__ bsum, int* __restrict__ rp, int nb, int n) {
    int l = threadIdx.x;
    int v = (l < nb) ? bsum[l] : 0;
    int inc = v;
    for (int off = 1; off < 64; off <<= 1) {
        int u = __shfl_up(inc, off);
        if (l >= off) inc += u;
    }
    int tot = __shfl(inc, 63);
    if (l < nb) bsum[l] = inc - v;
    if (l == 0) rp[n] = tot;
}

__global__ void k_scan_add(int* __restrict__ rp, const int* __restrict__ bsum, int n) {
    int b = blockIdx.x;
    int base_v = bsum[b];
    for (int i = threadIdx.x; i < 2048; i += TPB) {
        int idx = b * 2048 + i;
        if (idx < n) rp[idx] += base_v;
    }
}

__global__ void k_fill(const int* __restrict__ dst, const int* __restrict__ src,
                       const int* __restrict__ rank, const int* __restrict__ rp,
                       int* __restrict__ csrc, int e) {
    int i = blockIdx.x * TPB + threadIdx.x;
    if (i < e) csrc[rp[dst[i]] + rank[i]] = src[i];
}

// ---------------- W -> B-fragment pack (bf16) ----------------
__global__ void k_packW(const float* __restrict__ W, unsigned short* __restrict__ Bp) {
    int t = blockIdx.x * TPB + threadIdx.x;
    if (t >= 2048) return;
    int kb = t >> 7, n = t & 127;
    unsigned int w[4];
#pragma unroll
    for (int j = 0; j < 4; ++j) {
        unsigned int lo = f2bf(W[(kb * 8 + 2 * j) * 128 + n]);
        unsigned int hi = f2bf(W[(kb * 8 + 2 * j + 1) * 128 + n]);
        w[j] = lo | (hi << 16);
    }
    reinterpret_cast<uint4*>(Bp)[t] = make_uint4(w[0], w[1], w[2], w[3]);
}

// ---------------- MFMA bf16 GEMM + fused el/er, bf16 F output ----------------
// block tile 128x128; outputs: Fb (bf16 [N][128]), EL/ER ([N][4] fp32)
template <int MASKED, int BF16IN>
__global__ __launch_bounds__(TPB) void k_gemm_mfma(
    const void* __restrict__ Ain, const int* __restrict__ flag,
    const float* __restrict__ mtok, const unsigned short* __restrict__ Bpack,
    const float* __restrict__ al, const float* __restrict__ ar,
    unsigned short* __restrict__ Fb, float* __restrict__ EL, float* __restrict__ ER, int n)
{
    __shared__ char sAb[32768];            // bf16 [128][128], XOR-swizzled rows
    __shared__ unsigned short sB[16384];   // Bpack copy, linear
    int t = threadIdx.x;
    int bm0 = blockIdx.x * 128;

    for (int i = t; i < 2048; i += TPB)
        reinterpret_cast<uint4*>(sB)[i] = reinterpret_cast<const uint4*>(Bpack)[i];

    if (BF16IN) {
        const unsigned short* A = (const unsigned short*)Ain;
        for (int i = t; i < 2048; i += TPB) {   // 128 rows x 16 chunks of 16B
            int r = i >> 4, c = i & 15;
            int row = bm0 + r;
            uint4 v = make_uint4(0u, 0u, 0u, 0u);
            if (row < n) v = reinterpret_cast<const uint4*>(A + (size_t)row * 128)[c];
            int byte = r * 256 + ((c * 16) ^ ((r & 7) << 4));
            *reinterpret_cast<uint4*>(sAb + byte) = v;
        }
    } else {
        const float* A = (const float*)Ain;
        for (int i = t; i < 4096; i += TPB) {
            int r = i >> 5, c4 = i & 31;
            int row = bm0 + r;
            float4 v = make_float4(0.f, 0.f, 0.f, 0.f);
            if (row < n) {
                if (MASKED && flag[row]) v = reinterpret_cast<const float4*>(mtok)[c4];
                else v = reinterpret_cast<const float4*>(A + (size_t)row * 128)[c4];
            }
            ushort4 o;
            o.x = f2bf(v.x); o.y = f2bf(v.y); o.z = f2bf(v.z); o.w = f2bf(v.w);
            int byte = r * 256 + ((c4 * 8) ^ ((r & 7) << 4));
            *reinterpret_cast<ushort4*>(sAb + byte) = o;
        }
    }
    __syncthreads();

    int w = t >> 6, l = t & 63;
    int lm = l & 15, lg = l >> 4;
    const short8_t* bp = reinterpret_cast<const short8_t*>(sB);

    f32x4 acc[2][8];
#pragma unroll
    for (int mf = 0; mf < 2; ++mf)
#pragma unroll
        for (int f = 0; f < 8; ++f)
            acc[mf][f] = (f32x4){0.f, 0.f, 0.f, 0.f};

#pragma unroll
    for (int ks = 0; ks < 4; ++ks) {
        short8_t af[2];
#pragma unroll
        for (int mf = 0; mf < 2; ++mf) {
            int row = w * 32 + mf * 16 + lm;
            int byte = row * 256 + ((ks * 64 + lg * 16) ^ ((row & 7) << 4));
            af[mf] = *reinterpret_cast<const short8_t*>(sAb + byte);
        }
        int kb = ks * 4 + lg;
#pragma unroll
        for (int f = 0; f < 8; ++f) {
            short8_t bfr = bp[kb * 128 + f * 16 + lm];
            acc[0][f] = __builtin_amdgcn_mfma_f32_16x16x32_bf16(af[0], bfr, acc[0][f], 0, 0, 0);
            acc[1][f] = __builtin_amdgcn_mfma_f32_16x16x32_bf16(af[1], bfr, acc[1][f], 0, 0, 0);
        }
    }

    // epilogue: bf16 F store + fused el/er (D layout: row=(lane>>4)*4+reg, col=lane&15)
    float alv[8], arv[8];
#pragma unroll
    for (int f = 0; f < 8; ++f) { alv[f] = al[f * 16 + lm]; arv[f] = ar[f * 16 + lm]; }

#pragma unroll
    for (int mf = 0; mf < 2; ++mf) {
#pragma unroll
        for (int r = 0; r < 4; ++r) {
            int row = bm0 + w * 32 + mf * 16 + lg * 4 + r;
            if (row < n) {
#pragma unroll
                for (int f = 0; f < 8; ++f)
                    Fb[(size_t)row * 128 + f * 16 + lm] = f2bf(acc[mf][f][r]);
            }
            float pe[4], pr_[4];
#pragma unroll
            for (int h = 0; h < 4; ++h) {
                pe[h]  = acc[mf][2 * h][r] * alv[2 * h] + acc[mf][2 * h + 1][r] * alv[2 * h + 1];
                pr_[h] = acc[mf][2 * h][r] * arv[2 * h] + acc[mf][2 * h + 1][r] * arv[2 * h + 1];
            }
#pragma unroll
            for (int h = 0; h < 4; ++h) {
#pragma unroll
                for (int off = 1; off < 16; off <<= 1) {
                    pe[h]  += __shfl_xor(pe[h], off);
                    pr_[h] += __shfl_xor(pr_[h], off);
                }
            }
            if (lm == 0 && row < n) {
                *reinterpret_cast<float4*>(EL + (size_t)row * 4) = make_float4(pe[0], pe[1], pe[2], pe[3]);
                *reinterpret_cast<float4*>(ER + (size_t)row * 4) = make_float4(pr_[0], pr_[1], pr_[2], pr_[3]);
            }
        }
    }
}

// ---------------- node-centric softmax + aggregate (bf16 gather, bf16 out) ----------------
// wave per node; lane: edge-slot j = l>>4 (4 edges in flight), feature octet q = l&15
__global__ __launch_bounds__(TPB) void k_node_agg(
    const unsigned short* __restrict__ Fb,
    const float* __restrict__ EL, const float* __restrict__ ER,
    const float* __restrict__ bias,
    const int* __restrict__ rp, const int* __restrict__ csrc,
    unsigned short* __restrict__ OUT, int n)
{
    int l = threadIdx.x & 63;
    int v = blockIdx.x * 4 + (threadIdx.x >> 6);
    if (v >= n) return;
    int p0 = rp[v];
    int deg = rp[v + 1] - p0;
    int j = l >> 4, q = l & 15, h = q >> 2;

    if (deg == 0) {
        if (j == 0) {
            const float* bp = bias + q * 8;
            unsigned int od[4];
#pragma unroll
            for (int k = 0; k < 4; ++k) {
                float o0 = fmaxf(bp[2 * k], 0.f);
                float o1 = fmaxf(bp[2 * k + 1], 0.f);
                od[k] = (unsigned int)f2bf(o0) | ((unsigned int)f2bf(o1) << 16);
            }
            *reinterpret_cast<uint4*>(OUT + (size_t)v * 128 + q * 8) = make_uint4(od[0], od[1], od[2], od[3]);
        }
        return;
    }

    float er_h = ER[(size_t)v * 4 + h];
    float acc[8] = {};
    float ssum = 0.f;
    int nit = (deg + 3) >> 2;
    for (int it = 0; it < nit; ++it) {
        int e = it * 4 + j;
        bool valid = e < deg;
        int ec = valid ? e : (deg - 1);
        int s = csrc[p0 + ec];
        float x = __expf(lrelu(EL[(size_t)s * 4 + h] + er_h));
        x = valid ? x : 0.f;
        ssum += x;
        uint4 u = *reinterpret_cast<const uint4*>(Fb + (size_t)s * 128 + q * 8);
        acc[0] += x * bf_lo(u.x); acc[1] += x * bf_hi(u.x);
        acc[2] += x * bf_lo(u.y); acc[3] += x * bf_hi(u.y);
        acc[4] += x * bf_lo(u.z); acc[5] += x * bf_hi(u.z);
        acc[6] += x * bf_lo(u.w); acc[7] += x * bf_hi(u.w);
    }
#pragma unroll
    for (int k = 0; k < 8; ++k) {
        acc[k] += __shfl_xor(acc[k], 16);
        acc[k] += __shfl_xor(acc[k], 32);
    }
    ssum += __shfl_xor(ssum, 16);
    ssum += __shfl_xor(ssum, 32);
    if (j == 0) {
        float inv = 1.0f / ssum;
        const float* bp = bias + q * 8;
        unsigned int od[4];
#pragma unroll
        for (int k = 0; k < 4; ++k) {
            float o0 = fmaxf(acc[2 * k] * inv + bp[2 * k], 0.f);
            float o1 = fmaxf(acc[2 * k + 1] * inv + bp[2 * k + 1], 0.f);
            od[k] = (unsigned int)f2bf(o0) | ((unsigned int)f2bf(o1) << 16);
        }
        *reinterpret_cast<uint4*>(OUT + (size_t)v * 128 + q * 8) = make_uint4(od[0], od[1], od[2], od[3]);
    }
}

// ---------------- decoder GEMM on mask rows (bf16 H) + squared-diff partial ----------------
__global__ __launch_bounds__(TPB) void k_loss(
    const unsigned short* __restrict__ H, const int* __restrict__ midx,
    const float* __restrict__ Wd, const float* __restrict__ bd,
    const float* __restrict__ attr, int m, float* __restrict__ part)
{
    __shared__ float sA[32][128];
    __shared__ float sW[128][128];
    __shared__ int srow[32];
    __shared__ float red[TPB];
    int t = threadIdx.x;
    int bm0 = blockIdx.x * 32;
    if (t < 32) {
        int i = bm0 + t;
        srow[t] = (i < m) ? midx[i] : -1;
    }
    for (int i = t; i < 4096; i += TPB)
        reinterpret_cast<float4*>(&sW[0][0])[i] = reinterpret_cast<const float4*>(Wd)[i];
    __syncthreads();
    for (int i = t; i < 1024; i += TPB) {
        int r = i >> 5, c4 = i & 31;
        int node = srow[r];
        float4 v = make_float4(0.f, 0.f, 0.f, 0.f);
        if (node >= 0) {
            uint2 u = *reinterpret_cast<const uint2*>(H + (size_t)node * 128 + c4 * 4);
            v = make_float4(bf_lo(u.x), bf_hi(u.x), bf_lo(u.y), bf_hi(u.y));
        }
        reinterpret_cast<float4*>(&sA[r][0])[c4] = v;
    }
    __syncthreads();
    int lane = t & 63, wave = t >> 6;
    int half = lane >> 5;
    int c0 = (lane & 31) * 4;
    int r0 = wave * 8 + half * 4;
    float acc[4][4] = {};
#pragma unroll 8
    for (int k = 0; k < 128; ++k) {
        float4 wv = *reinterpret_cast<const float4*>(&sW[k][c0]);
#pragma unroll
        for (int r = 0; r < 4; ++r) {
            float a = sA[r0 + r][k];
            acc[r][0] += a * wv.x;
            acc[r][1] += a * wv.y;
            acc[r][2] += a * wv.z;
            acc[r][3] += a * wv.w;
        }
    }
    float local = 0.f;
    float4 bv = *reinterpret_cast<const float4*>(bd + c0);
#pragma unroll
    for (int r = 0; r < 4; ++r) {
        int i = bm0 + r0 + r;
        if (i < m) {
            int node = srow[r0 + r];
            float4 at = *reinterpret_cast<const float4*>(attr + (size_t)node * 128 + c0);
            float d0 = acc[r][0] + bv.x - at.x;
            float d1 = acc[r][1] + bv.y - at.y;
            float d2 = acc[r][2] + bv.z - at.z;
            float d3 = acc[r][3] + bv.w - at.w;
            local += d0 * d0 + d1 * d1 + d2 * d2 + d3 * d3;
        }
    }
    red[t] = local;
    __syncthreads();
    for (int off = TPB / 2; off > 0; off >>= 1) {
        if (t < off) red[t] += red[t + off];
        __syncthreads();
    }
    if (t == 0) part[blockIdx.x] = red[0];
}

__global__ void k_final(const float* __restrict__ part, int np, double inv_denom,
                        float* __restrict__ out)
{
    __shared__ double red[TPB];
    int t = threadIdx.x;
    double s = 0.0;
    for (int i = t; i < np; i += TPB) s += (double)part[i];
    red[t] = s;
    __syncthreads();
    for (int off = TPB / 2; off > 0; off >>= 1) {
        if (t < off) red[t] += red[t + off];
        __syncthreads();
    }
    if (t == 0) out[0] = (float)(red[0] * inv_denom);
}

// ---------------- launch ----------------
extern "C" void kernel_launch(void* const* d_in, const int* in_sizes, int n_in,
                              void* d_out, int out_size, void* d_ws, size_t ws_size,
                              hipStream_t stream)
{
    const float* attr = (const float*)d_in[0];
    const int*   src  = (const int*)d_in[1];
    const int*   dst  = (const int*)d_in[2];
    const int*   midx = (const int*)d_in[3];
    const float* W0   = (const float*)d_in[4];
    const float* al0  = (const float*)d_in[5];
    const float* ar0  = (const float*)d_in[6];
    const float* b0   = (const float*)d_in[7];
    const float* W1   = (const float*)d_in[8];
    const float* al1  = (const float*)d_in[9];
    const float* ar1  = (const float*)d_in[10];
    const float* b1   = (const float*)d_in[11];
    const float* Wd   = (const float*)d_in[12];
    const float* bd   = (const float*)d_in[13];
    const float* mtok = (const float*)d_in[14];

    int N = in_sizes[0] / 128;
    int E = in_sizes[1];
    int M = in_sizes[3];

    char* p = (char*)d_ws;
    auto carve = [&](size_t bytes) {
        char* q = p;
        p += (bytes + 255) & ~(size_t)255;
        return q;
    };
    unsigned short* fb = (unsigned short*)carve((size_t)N * 128 * 2);  // bf16 messages
    unsigned short* hb = (unsigned short*)carve((size_t)N * 128 * 2);  // bf16 layer output
    float* el   = (float*)carve((size_t)N * 4 * 4);
    float* er   = (float*)carve((size_t)N * 4 * 4);
    int*   flag = (int*)carve((size_t)N * 4);
    int*   cnt  = (int*)carve((size_t)N * 4);
    int*   rp   = (int*)carve((size_t)(N + 1) * 4);
    int*   rank = (int*)carve((size_t)E * 4);
    int*   csrc = (int*)carve((size_t)E * 4);
    unsigned short* bp0 = (unsigned short*)carve(16 * 128 * 8 * 2);
    unsigned short* bp1 = (unsigned short*)carve(16 * 128 * 8 * 2);
    int NB = (N + 2047) / 2048;
    int*   bsum = (int*)carve((size_t)NB * 4);
    int NLB = (M + 31) / 32;
    float* part = (float*)carve((size_t)NLB * 4);
    (void)ws_size; (void)n_in; (void)out_size;

    hipMemsetAsync(flag, 0, (size_t)N * 4, stream);
    hipMemsetAsync(cnt, 0, (size_t)N * 4, stream);

    k_setflag<<<(M + TPB - 1) / TPB, TPB, 0, stream>>>(midx, flag, M);
    k_count_rank<<<(E + TPB - 1) / TPB, TPB, 0, stream>>>(dst, cnt, rank, E);
    k_scan_block<<<NB, TPB, 0, stream>>>(cnt, rp, bsum, N);
    k_scan_sums<<<1, 64, 0, stream>>>(bsum, rp, NB, N);
    k_scan_add<<<NB, TPB, 0, stream>>>(rp, bsum, N);
    k_fill<<<(E + TPB - 1) / TPB, TPB, 0, stream>>>(dst, src, rank, rp, csrc, E);
    k_packW<<<8, TPB, 0, stream>>>(W0, bp0);
    k_packW<<<8, TPB, 0, stream>>>(W1, bp1);

    int GB = (N + 127) / 128;
    int NAB = (N + 3) / 4;
    // layer 0
    k_gemm_mfma<1, 0><<<GB, TPB, 0, stream>>>(attr, flag, mtok, bp0, al0, ar0, fb, el, er, N);
    k_node_agg<<<NAB, TPB, 0, stream>>>(fb, el, er, b0, rp, csrc, hb, N);
    // layer 1
    k_gemm_mfma<0, 1><<<GB, TPB, 0, stream>>>(hb, nullptr, nullptr, bp1, al1, ar1, fb, el, er, N);
    k_node_agg<<<NAB, TPB, 0, stream>>>(fb, el, er, b1, rp, csrc, hb, N);
    // decoder + loss
    k_loss<<<NLB, TPB, 0, stream>>>(hb, midx, Wd, bd, attr, M, part);
    k_final<<<1, TPB, 0, stream>>>(part, NLB, 1.0 / ((double)M * 128.0), (float*)d_out);
}